// Round 11
// baseline (315.223 us; speedup 1.0000x reference)
//
#include <hip/hip_runtime.h>
#include <hip/hip_bf16.h>
#include <cstdint>

#define CIN 128
#define NH 8
#define CH 32

typedef short bf16x8 __attribute__((ext_vector_type(8)));
typedef short bf16x4 __attribute__((ext_vector_type(4)));
typedef float f32x4 __attribute__((ext_vector_type(4)));

__device__ __forceinline__ short f2bf(float f) {
  union { float f; unsigned u; } v; v.f = f;
  unsigned r = (v.u + 0x7FFFu + ((v.u >> 16) & 1u)) >> 16;   // RNE
  return (short)r;
}
__device__ __forceinline__ float bf2f(short s) {
  union { unsigned u; float f; } v; v.u = ((unsigned)(unsigned short)s) << 16;
  return v.f;
}
__device__ __forceinline__ unsigned pk2bf(float a, float b) {
  union { __hip_bfloat162 h; unsigned u; } cv;
  cv.h = __float22bfloat162_rn(make_float2(a, b));
  return cv.u;
}

// ---------------- prep: weights->bf16 [n][k] | mask detect ----------------
// blocks 0..63: WT/WoT ; 64: detect_mask
__global__ __launch_bounds__(256) void prep(
    const float* __restrict__ Wq, const float* __restrict__ Wk,
    const float* __restrict__ Wv, const float* __restrict__ Wg,
    const float* __restrict__ Wo,
    const uint4* __restrict__ mask,
    short* __restrict__ WT, short* __restrict__ WoT,
    unsigned int* __restrict__ flag)
{
  __shared__ int viol;
  const int b = blockIdx.x;
  if (b < 64) {
    const float qscale = 0.17677669529663689f;  // 1/sqrt(32)
#pragma unroll
    for (int e = 0; e < 10; ++e) {
      int o = b * 2560 + e * 256 + threadIdx.x;
      if (o < 131072) {
        int n = o >> 7, k = o & 127;
        int seg = n >> 8, nn = n & 255;
        const float* W = (seg == 0) ? Wq : (seg == 1) ? Wk : (seg == 2) ? Wv : Wg;
        float v = W[k * 256 + nn];
        if (seg == 0) v *= qscale;
        WT[o] = f2bf(v);
      } else {
        int o2 = o - 131072;
        int n = o2 >> 8, k = o2 & 255;
        WoT[o2] = f2bf(Wo[k * 128 + n]);
      }
    }
  } else {
    if (threadIdx.x == 0) viol = 0;
    __syncthreads();
    int v = 0;
#pragma unroll
    for (int j = 0; j < 16; ++j) {
      uint4 w = mask[j * 256 + threadIdx.x];
      v |= (w.x > 1u) | (w.y > 1u) | (w.z > 1u) | (w.w > 1u);
    }
    if (v) atomicOr(&viol, 1);
    __syncthreads();
    if (threadIdx.x == 0) *flag = viol ? 0u : 1u;
  }
}

// ---------------- mega-fused v3: 2 co-resident blocks per srow (q-split) --------------
// Grid 512: block = (srow = bid>>1, half = bid&1). 512 thr = 8 waves.
// Wave owns 16 q-rows (qrowL = w*16 local; global = half*128 + w*16) -> acc_out = 32 regs
// and 32 key-rows {keyA = half*128+w*16 (== q rows), keyB = (1-half)*128+w*16} -> the
// union over 8 waves covers all 256 keys; K/V proj duplicated across the block pair
// (+18% MFMA) buys 2 blocks/CU = 16 waves/CU.
// ALLOCATOR CONTRACT (R8/R10 lesson): allocator targets LDS-allowed max occupancy and
// caps VGPR to it. LDS = 58400 B in (54613, 81920] => exactly 2 blocks/CU => 4 waves/EU
// => VGPR cap 128 >= ~115 working set. qL is over-allocated to 256 rows for this.
// x rows in registers (xfA/xfB, 32 VGPR). Layouts + attn body verbatim from R9/R10
// (both harness-passed). Out rows disjoint across blocks -> no atomics.
__global__ __launch_bounds__(512) void fused_attn(
    const float* __restrict__ x, const short* __restrict__ WT,
    const short* __restrict__ WoT,
    const float* __restrict__ bias, const float* __restrict__ bg,
    const float* __restrict__ bo,
    const void* __restrict__ maskraw, const unsigned int* __restrict__ flagp,
    float* __restrict__ out)
{
  __shared__ __align__(16) short lds16[29200];
  short* kL = lds16;                                    // [256][40] bf16
  short* vL = &lds16[10240];                            // [32][264] bf16
  short* qL = &lds16[18688];                            // [256][40] (128 used; oversize = LDS pad)
  float* lL = (float*)&lds16[28928];                    // 128 f32
  unsigned int* scratch = (unsigned int*)&lds16[29184]; // 8 u32

  const int tid = threadIdx.x;
  const int srow = blockIdx.x >> 1;
  const int half = blockIdx.x & 1;
  const int lane = tid & 63, w = tid >> 6;
  const int g = lane >> 4, c16 = lane & 15;
  const int keyA = half * 128 + w * 16;      // == this wave's global q-row base
  const int keyB = (128 - half * 128) + w * 16;
  const int qlocal = w * 16;

  // ---- mask row -> 8x u32 bits (waves 0..3) ----
  const unsigned int fl = *flagp;
  if (tid < 256) {
    int mv = fl ? ((const int*)maskraw)[srow * 256 + tid]
                : (int)((const unsigned char*)maskraw)[srow * 256 + tid];
    unsigned long long bb = __ballot(mv != 0);
    if (lane == 0) {
      scratch[w * 2 + 0] = (unsigned int)bb;
      scratch[w * 2 + 1] = (unsigned int)(bb >> 32);
    }
  }

  // ---- x rows keyA+c16 / keyB+c16 -> register fragments (chans kk*32+g*8..+7) ----
  bf16x8 xfA[4], xfB[4];
  {
    const float* xsA = x + ((size_t)srow * 256 + keyA + c16) * 128 + g * 8;
    const float* xsB = x + ((size_t)srow * 256 + keyB + c16) * 128 + g * 8;
#pragma unroll
    for (int kk = 0; kk < 4; ++kk) {
      float4 a = *(const float4*)(xsA + kk * 32);
      float4 b = *(const float4*)(xsA + kk * 32 + 4);
      union { unsigned u[4]; bf16x8 v; } p;
      p.u[0] = pk2bf(a.x, a.y); p.u[1] = pk2bf(a.z, a.w);
      p.u[2] = pk2bf(b.x, b.y); p.u[3] = pk2bf(b.z, b.w);
      xfA[kk] = p.v;
      a = *(const float4*)(xsB + kk * 32);
      b = *(const float4*)(xsB + kk * 32 + 4);
      p.u[0] = pk2bf(a.x, a.y); p.u[1] = pk2bf(a.z, a.w);
      p.u[2] = pk2bf(b.x, b.y); p.u[3] = pk2bf(b.z, b.w);
      xfB[kk] = p.v;
    }
  }

  __syncthreads();   // scratch visible

  unsigned int mb[8];
#pragma unroll
  for (int j = 0; j < 8; ++j)
    mb[j] = (unsigned int)__builtin_amdgcn_readfirstlane((int)scratch[j]);

  const f32x4 zero4 = {0.f, 0.f, 0.f, 0.f};
  f32x4 acc_out[8];
#pragma unroll
  for (int ct = 0; ct < 8; ++ct) acc_out[ct] = zero4;

#pragma unroll 1
  for (int h = 0; h < 8; ++h) {
    {
      // ---- K (seg1): 32 keys (A,B) x 32 chans -> kL[key][chan] ----
      f32x4 aA0 = zero4, aA1 = zero4, aB0 = zero4, aB1 = zero4;
#pragma unroll
      for (int kk = 0; kk < 4; ++kk) {
        bf16x8 w0 = *(const bf16x8*)(WT + (size_t)(256 + h * CH + c16) * 128 + kk * 32 + g * 8);
        bf16x8 w1 = *(const bf16x8*)(WT + (size_t)(256 + h * CH + 16 + c16) * 128 + kk * 32 + g * 8);
        aA0 = __builtin_amdgcn_mfma_f32_16x16x32_bf16(w0, xfA[kk], aA0, 0, 0, 0);
        aA1 = __builtin_amdgcn_mfma_f32_16x16x32_bf16(w1, xfA[kk], aA1, 0, 0, 0);
        aB0 = __builtin_amdgcn_mfma_f32_16x16x32_bf16(w0, xfB[kk], aB0, 0, 0, 0);
        aB1 = __builtin_amdgcn_mfma_f32_16x16x32_bf16(w1, xfB[kk], aB1, 0, 0, 0);
      }
      union { unsigned u[2]; bf16x4 v; } p;
      p.u[0] = pk2bf(aA0[0], aA0[1]); p.u[1] = pk2bf(aA0[2], aA0[3]);
      *(bf16x4*)&kL[(keyA + c16) * 40 + g * 4] = p.v;
      p.u[0] = pk2bf(aA1[0], aA1[1]); p.u[1] = pk2bf(aA1[2], aA1[3]);
      *(bf16x4*)&kL[(keyA + c16) * 40 + 16 + g * 4] = p.v;
      p.u[0] = pk2bf(aB0[0], aB0[1]); p.u[1] = pk2bf(aB0[2], aB0[3]);
      *(bf16x4*)&kL[(keyB + c16) * 40 + g * 4] = p.v;
      p.u[0] = pk2bf(aB1[0], aB1[1]); p.u[1] = pk2bf(aB1[2], aB1[3]);
      *(bf16x4*)&kL[(keyB + c16) * 40 + 16 + g * 4] = p.v;
    }
    {
      // ---- V (seg2, swapped): keys (A,B) -> vL[chan][key] ----
      f32x4 aA0 = zero4, aA1 = zero4, aB0 = zero4, aB1 = zero4;
#pragma unroll
      for (int kk = 0; kk < 4; ++kk) {
        bf16x8 w0 = *(const bf16x8*)(WT + (size_t)(512 + h * CH + c16) * 128 + kk * 32 + g * 8);
        bf16x8 w1 = *(const bf16x8*)(WT + (size_t)(512 + h * CH + 16 + c16) * 128 + kk * 32 + g * 8);
        aA0 = __builtin_amdgcn_mfma_f32_16x16x32_bf16(xfA[kk], w0, aA0, 0, 0, 0);
        aA1 = __builtin_amdgcn_mfma_f32_16x16x32_bf16(xfA[kk], w1, aA1, 0, 0, 0);
        aB0 = __builtin_amdgcn_mfma_f32_16x16x32_bf16(xfB[kk], w0, aB0, 0, 0, 0);
        aB1 = __builtin_amdgcn_mfma_f32_16x16x32_bf16(xfB[kk], w1, aB1, 0, 0, 0);
      }
      union { unsigned u[2]; bf16x4 v; } p;
      p.u[0] = pk2bf(aA0[0], aA0[1]); p.u[1] = pk2bf(aA0[2], aA0[3]);
      *(bf16x4*)&vL[(size_t)c16 * 264 + keyA + g * 4] = p.v;
      p.u[0] = pk2bf(aA1[0], aA1[1]); p.u[1] = pk2bf(aA1[2], aA1[3]);
      *(bf16x4*)&vL[(size_t)(16 + c16) * 264 + keyA + g * 4] = p.v;
      p.u[0] = pk2bf(aB0[0], aB0[1]); p.u[1] = pk2bf(aB0[2], aB0[3]);
      *(bf16x4*)&vL[(size_t)c16 * 264 + keyB + g * 4] = p.v;
      p.u[0] = pk2bf(aB1[0], aB1[1]); p.u[1] = pk2bf(aB1[2], aB1[3]);
      *(bf16x4*)&vL[(size_t)(16 + c16) * 264 + keyB + g * 4] = p.v;
    }
    {
      // ---- Q (seg0, scale pre-folded): own q rows (== keyA rows) -> qL[qlocal][chan] ----
      f32x4 a0 = zero4, a1 = zero4;
#pragma unroll
      for (int kk = 0; kk < 4; ++kk) {
        bf16x8 w0 = *(const bf16x8*)(WT + (size_t)(h * CH + c16) * 128 + kk * 32 + g * 8);
        bf16x8 w1 = *(const bf16x8*)(WT + (size_t)(h * CH + 16 + c16) * 128 + kk * 32 + g * 8);
        a0 = __builtin_amdgcn_mfma_f32_16x16x32_bf16(w0, xfA[kk], a0, 0, 0, 0);
        a1 = __builtin_amdgcn_mfma_f32_16x16x32_bf16(w1, xfA[kk], a1, 0, 0, 0);
      }
      union { unsigned u[2]; bf16x4 v; } p;
      p.u[0] = pk2bf(a0[0], a0[1]); p.u[1] = pk2bf(a0[2], a0[3]);
      *(bf16x4*)&qL[(qlocal + c16) * 40 + g * 4] = p.v;
      p.u[0] = pk2bf(a1[0], a1[1]); p.u[1] = pk2bf(a1[2], a1[3]);
      *(bf16x4*)&qL[(qlocal + c16) * 40 + 16 + g * 4] = p.v;
    }
    __syncthreads();   // A: kL/vL visible to all waves

    // ================= attention (R10 body: 16 q-rows/wave) =================
    bf16x8 qf = *(const bf16x8*)&qL[(qlocal + c16) * 40 + g * 8];
    float l_ = 0.f;
    f32x4 O0 = zero4, O1 = zero4;
    const float* bh = bias + (size_t)h * 65536 + (size_t)(half * 128) * 256;

#pragma unroll 1
    for (int ch = 0; ch < 8; ++ch) {
      float4 bb0 = *(const float4*)(bh + (size_t)(qlocal + c16) * 256 + ch * 32 + g * 4);
      float4 bb1 = *(const float4*)(bh + (size_t)(qlocal + c16) * 256 + ch * 32 + 16 + g * 4);
#pragma unroll
      for (int kt = 0; kt < 2; ++kt) {
        bf16x8 kf = *(const bf16x8*)&kL[(ch * 32 + kt * 16 + c16) * 40 + g * 8];
        bf16x4 vlo = *(const bf16x4*)&vL[(size_t)c16 * 264 + ch * 32 + kt * 16 + g * 4];
        bf16x4 vhi = *(const bf16x4*)&vL[(size_t)(16 + c16) * 264 + ch * 32 + kt * 16 + g * 4];
        const unsigned nib = (mb[ch] >> (kt * 16 + g * 4)) & 0xFu;
        float em0 = (nib & 1u) ? 1.f : 0.f;
        float em1 = (nib & 2u) ? 1.f : 0.f;
        float em2 = (nib & 4u) ? 1.f : 0.f;
        float em3 = (nib & 8u) ? 1.f : 0.f;
        const float4 bb = kt ? bb1 : bb0;
        f32x4 S = __builtin_amdgcn_mfma_f32_16x16x32_bf16(kf, qf, zero4, 0, 0, 0);
        float p0 = em0 * __expf(fminf(S[0] + bb.x, 85.f));
        float p1 = em1 * __expf(fminf(S[1] + bb.y, 85.f));
        float p2 = em2 * __expf(fminf(S[2] + bb.z, 85.f));
        float p3 = em3 * __expf(fminf(S[3] + bb.w, 85.f));
        l_ += (p0 + p1) + (p2 + p3);
        union { unsigned u[2]; bf16x4 v; } pu;
        pu.u[0] = pk2bf(p0, p1);
        pu.u[1] = pk2bf(p2, p3);
        O0 = __builtin_amdgcn_mfma_f32_16x16x16bf16_1k(pu.v, vlo, O0, 0, 0, 0);
        O1 = __builtin_amdgcn_mfma_f32_16x16x16bf16_1k(pu.v, vhi, O1, 0, 0, 0);
      }
    }

    // ---- l reduction over 4 g-groups (wave-local) ----
    {
      float v = l_;
      v += __shfl_xor(v, 16);
      v += __shfl_xor(v, 32);
      if (lane < 16) lL[qlocal + c16] = v;
    }

    // ---- G (seg3, swapped) -> regs, deferred (not live during attn) ----
    f32x4 ga0 = zero4, ga1 = zero4;
#pragma unroll
    for (int kk = 0; kk < 4; ++kk) {
      bf16x8 w0 = *(const bf16x8*)(WT + (size_t)(768 + h * CH + c16) * 128 + kk * 32 + g * 8);
      bf16x8 w1 = *(const bf16x8*)(WT + (size_t)(768 + h * CH + 16 + c16) * 128 + kk * 32 + g * 8);
      ga0 = __builtin_amdgcn_mfma_f32_16x16x32_bf16(xfA[kk], w0, ga0, 0, 0, 0);
      ga1 = __builtin_amdgcn_mfma_f32_16x16x32_bf16(xfA[kk], w1, ga1, 0, 0, 0);
    }

    // ---- epilogue: gated O -> bf16 -> qL reused as oL (wave-private rows) ----
    {
      float bgl0 = bg[h * CH + c16];
      float bgl1 = bg[h * CH + 16 + c16];
#pragma unroll
      for (int i = 0; i < 4; ++i) {
        float inv = 1.f / lL[qlocal + g * 4 + i];
        float g0 = 1.f / (1.f + __expf(-(ga0[i] + bgl0)));
        float g1 = 1.f / (1.f + __expf(-(ga1[i] + bgl1)));
        qL[(qlocal + g * 4 + i) * 40 + c16]      = f2bf(O0[i] * inv * g0);
        qL[(qlocal + g * 4 + i) * 40 + 16 + c16] = f2bf(O1[i] * inv * g1);
      }
    }

    // ---- out accumulation: acc_out[ct] += O_h (16x32) @ Wo[h*32..][ct*16..] ----
    {
      bf16x8 of = *(const bf16x8*)&qL[(qlocal + c16) * 40 + g * 8];
#pragma unroll
      for (int ct = 0; ct < 8; ++ct) {
        bf16x8 wo = *(const bf16x8*)(WoT + (size_t)(ct * 16 + c16) * 256 + h * 32 + g * 8);
        acc_out[ct] = __builtin_amdgcn_mfma_f32_16x16x32_bf16(of, wo, acc_out[ct], 0, 0, 0);
      }
    }
    __syncthreads();   // B: kL/vL reads done before next head's proj overwrites
  }

  // ---- final: out = acc_out + bo (rows disjoint across the block pair) ----
#pragma unroll
  for (int ct = 0; ct < 8; ++ct) {
    float bv = bo[ct * 16 + c16];
#pragma unroll
    for (int i = 0; i < 4; ++i)
      out[((size_t)srow * 256 + half * 128 + qlocal + g * 4 + i) * 128 + ct * 16 + c16] =
          acc_out[ct][i] + bv;
  }
}

extern "C" void kernel_launch(void* const* d_in, const int* in_sizes, int n_in,
                              void* d_out, int out_size, void* d_ws, size_t ws_size,
                              hipStream_t stream) {
  const float* x    = (const float*)d_in[0];
  const float* bias = (const float*)d_in[1];
  const void*  mask = d_in[2];
  const float* Wq   = (const float*)d_in[3];
  const float* Wk   = (const float*)d_in[4];
  const float* Wv   = (const float*)d_in[5];
  const float* Wo   = (const float*)d_in[6];
  const float* bo   = (const float*)d_in[7];
  const float* Wg   = (const float*)d_in[8];
  const float* bg   = (const float*)d_in[9];
  float* out = (float*)d_out;

  // ws: [flag 256B][WT 256KB][WoT 64KB]
  unsigned int* flag = (unsigned int*)d_ws;
  short* WT  = (short*)((char*)d_ws + 256);
  short* WoT = WT + 131072;

  prep<<<65, 256, 0, stream>>>(Wq, Wk, Wv, Wg, Wo, (const uint4*)mask,
                               WT, WoT, flag);
  fused_attn<<<512, 512, 0, stream>>>(x, WT, WoT, bias, bg, bo,
                                      mask, flag, out);
}

// Round 12
// 239.641 us; speedup vs baseline: 1.3154x; 1.3154x over previous
//
#include <hip/hip_runtime.h>
#include <hip/hip_bf16.h>
#include <cstdint>

#define CIN 128
#define NH 8
#define CH 32

typedef short bf16x8 __attribute__((ext_vector_type(8)));
typedef short bf16x4 __attribute__((ext_vector_type(4)));
typedef float f32x4 __attribute__((ext_vector_type(4)));

__device__ __forceinline__ short f2bf(float f) {
  union { float f; unsigned u; } v; v.f = f;
  unsigned r = (v.u + 0x7FFFu + ((v.u >> 16) & 1u)) >> 16;   // RNE
  return (short)r;
}
__device__ __forceinline__ float bf2f(short s) {
  union { unsigned u; float f; } v; v.u = ((unsigned)(unsigned short)s) << 16;
  return v.f;
}
__device__ __forceinline__ unsigned pk2bf(float a, float b) {
  union { __hip_bfloat162 h; unsigned u; } cv;
  cv.h = __float22bfloat162_rn(make_float2(a, b));
  return cv.u;
}

// ---------------- prep v2: coalesced 64x64 LDS tile-transpose | mask detect ----------
// Old prep read W[k*256+n] at 1KB stride (scatter) on a 65-block grid: latency-bound,
// inferred ~79 us. v2: coalesced float4 row reads -> bf16 tile [64][68] (pad: store
// phase is a 4-way LDS conflict, immaterial) -> coalesced bf16x4 row writes.
// blocks 0..31: Wq/Wk/Wv/Wg tiles (seg = b>>3; kt = (b&7)>>2; nt = b&3)
// blocks 32..39: Wo tiles (kt = (b-32)>>1; nt = (b-32)&1)
// block 40: mask detect (unchanged logic).
// Values bit-identical to old prep: f2bf(W * qs), qs = 1/sqrt(32) for seg 0 only.
__global__ __launch_bounds__(256) void prep(
    const float* __restrict__ Wq, const float* __restrict__ Wk,
    const float* __restrict__ Wv, const float* __restrict__ Wg,
    const float* __restrict__ Wo,
    const uint4* __restrict__ mask,
    short* __restrict__ WT, short* __restrict__ WoT,
    unsigned int* __restrict__ flag)
{
  const int b = blockIdx.x;
  const int tid = threadIdx.x;
  if (b < 40) {
    __shared__ short tile[64 * 68];
    const int rr = tid >> 4;   // 0..15
    const int cc = tid & 15;   // 0..15
    if (b < 32) {
      const int seg = b >> 3, sub = b & 7, kt = sub >> 2, nt = sub & 3;
      const int k0 = kt * 64, n0 = nt * 64;
      const float* W = (seg == 0) ? Wq : (seg == 1) ? Wk : (seg == 2) ? Wv : Wg;
      const float qs = (seg == 0) ? 0.17677669529663689f : 1.0f;
#pragma unroll
      for (int p = 0; p < 4; ++p) {
        int r = p * 16 + rr;
        float4 a = *(const float4*)(W + (size_t)(k0 + r) * 256 + n0 + cc * 4);
        tile[r * 68 + cc * 4 + 0] = f2bf(a.x * qs);
        tile[r * 68 + cc * 4 + 1] = f2bf(a.y * qs);
        tile[r * 68 + cc * 4 + 2] = f2bf(a.z * qs);
        tile[r * 68 + cc * 4 + 3] = f2bf(a.w * qs);
      }
      __syncthreads();
#pragma unroll
      for (int p = 0; p < 4; ++p) {
        int rn = p * 16 + rr;
        bf16x4 v;
        v[0] = tile[(cc * 4 + 0) * 68 + rn];
        v[1] = tile[(cc * 4 + 1) * 68 + rn];
        v[2] = tile[(cc * 4 + 2) * 68 + rn];
        v[3] = tile[(cc * 4 + 3) * 68 + rn];
        *(bf16x4*)(WT + (size_t)(seg * 256 + n0 + rn) * 128 + k0 + cc * 4) = v;
      }
    } else {
      const int sub = b - 32, kt = sub >> 1, nt = sub & 1;
      const int k0 = kt * 64, n0 = nt * 64;
#pragma unroll
      for (int p = 0; p < 4; ++p) {
        int r = p * 16 + rr;
        float4 a = *(const float4*)(Wo + (size_t)(k0 + r) * 128 + n0 + cc * 4);
        tile[r * 68 + cc * 4 + 0] = f2bf(a.x);
        tile[r * 68 + cc * 4 + 1] = f2bf(a.y);
        tile[r * 68 + cc * 4 + 2] = f2bf(a.z);
        tile[r * 68 + cc * 4 + 3] = f2bf(a.w);
      }
      __syncthreads();
#pragma unroll
      for (int p = 0; p < 4; ++p) {
        int rn = p * 16 + rr;
        bf16x4 v;
        v[0] = tile[(cc * 4 + 0) * 68 + rn];
        v[1] = tile[(cc * 4 + 1) * 68 + rn];
        v[2] = tile[(cc * 4 + 2) * 68 + rn];
        v[3] = tile[(cc * 4 + 3) * 68 + rn];
        *(bf16x4*)(WoT + (size_t)(n0 + rn) * 256 + k0 + cc * 4) = v;
      }
    }
  } else {
    __shared__ int viol;
    if (tid == 0) viol = 0;
    __syncthreads();
    int v = 0;
#pragma unroll
    for (int j = 0; j < 16; ++j) {
      uint4 w = mask[j * 256 + tid];
      v |= (w.x > 1u) | (w.y > 1u) | (w.z > 1u) | (w.w > 1u);
    }
    if (v) atomicOr(&viol, 1);
    __syncthreads();
    if (tid == 0) *flag = viol ? 0u : 1u;
  }
}

// ---------------- mega-fused: QKVG-proj + flash attn + out-proj, 1 block/srow ----------
// R9 VERBATIM (measured 163 us, VGPR 116, no spill). 512 thr = 8 waves, wave owns 32
// rows, x staged once in xl (LDS). LDS kept at ~128.5 KB ON PURPOSE: >80 KB forces the
// register allocator to see a 1-block/CU cap (grid is 256 = 1/CU anyway), so it won't
// strangle VGPRs for a phantom 2nd block (R8/R10/R11 failures: small LDS -> 60-76 VGPR
// cap -> rematerialization storm).
__global__ __launch_bounds__(512) void fused_attn(
    const float* __restrict__ x, const short* __restrict__ WT,
    const short* __restrict__ WoT,
    const float* __restrict__ bias, const float* __restrict__ bg,
    const float* __restrict__ bo,
    const void* __restrict__ maskraw, const unsigned int* __restrict__ flagp,
    float* __restrict__ out)
{
  __shared__ __align__(16) short xl[256 * 136];   // 69632 B
  __shared__ __align__(16) short kL[256 * 40];    // 20480 B [key][chan]
  __shared__ __align__(16) short vL[32 * 264];    // 16896 B [chan][key]
  __shared__ __align__(16) short qL[256 * 40];    // 20480 B [q][chan]; reused as oL
  __shared__ float lL[256];
  __shared__ unsigned int scratch[8];

  const int tid = threadIdx.x;
  const int srow = blockIdx.x;
  const int lane = tid & 63, w = tid >> 6;
  const int g = lane >> 4, c16 = lane & 15;
  const int myrow = w * 32;

  // ---- mask row -> 8x u32 bits (waves 0..3) ----
  const unsigned int fl = *flagp;
  if (tid < 256) {
    int mv = fl ? ((const int*)maskraw)[srow * 256 + tid]
                : (int)((const unsigned char*)maskraw)[srow * 256 + tid];
    unsigned long long bb = __ballot(mv != 0);
    if (lane == 0) {
      scratch[w * 2 + 0] = (unsigned int)bb;
      scratch[w * 2 + 1] = (unsigned int)(bb >> 32);
    }
  }

  // ---- stage x-slice f32 -> bf16 xl[256][136] ----
  {
    const float* xs = x + (size_t)srow * 256 * 128;
#pragma unroll
    for (int it = 0; it < 16; ++it) {
      int idx = it * 512 + tid;          // float4 index
      int row = idx >> 5, c4 = idx & 31;
      float4 a = *(const float4*)(xs + (size_t)idx * 4);
      union { unsigned u[2]; bf16x4 v; } pu;
      pu.u[0] = pk2bf(a.x, a.y);
      pu.u[1] = pk2bf(a.z, a.w);
      *(bf16x4*)&xl[row * 136 + c4 * 4] = pu.v;
    }
  }
  __syncthreads();

  unsigned int mb[8];
#pragma unroll
  for (int j = 0; j < 8; ++j) mb[j] = scratch[j];

  const f32x4 zero4 = {0.f, 0.f, 0.f, 0.f};
  f32x4 acc_out[2][8];
#pragma unroll
  for (int qt = 0; qt < 2; ++qt)
#pragma unroll
    for (int ct = 0; ct < 8; ++ct) acc_out[qt][ct] = zero4;

#pragma unroll 1
  for (int h = 0; h < 8; ++h) {
    f32x4 ga[2][2];   // raw G: ga[rt][ct][i] = G[q=myrow+rt*16+g*4+i][chan=ct*16+c16]
    // ================= projection phase =================
    // K: mfma(Wf,xf): lane = K[chan ct*16+g*4+j][key myrow+rt*16+c16] -> kL[key][chan]
    {
      f32x4 acc[2][2];
#pragma unroll
      for (int ct = 0; ct < 2; ++ct)
#pragma unroll
        for (int rt = 0; rt < 2; ++rt) acc[ct][rt] = zero4;
#pragma unroll
      for (int kk = 0; kk < 4; ++kk) {
        bf16x8 wf[2], xf[2];
#pragma unroll
        for (int ct = 0; ct < 2; ++ct)
          wf[ct] = *(const bf16x8*)(WT + (size_t)(256 + h * CH + ct * 16 + c16) * 128 + kk * 32 + g * 8);
#pragma unroll
        for (int rt = 0; rt < 2; ++rt)
          xf[rt] = *(const bf16x8*)&xl[(myrow + rt * 16 + c16) * 136 + kk * 32 + g * 8];
#pragma unroll
        for (int ct = 0; ct < 2; ++ct)
#pragma unroll
          for (int rt = 0; rt < 2; ++rt)
            acc[ct][rt] = __builtin_amdgcn_mfma_f32_16x16x32_bf16(wf[ct], xf[rt], acc[ct][rt], 0, 0, 0);
      }
#pragma unroll
      for (int ct = 0; ct < 2; ++ct)
#pragma unroll
        for (int rt = 0; rt < 2; ++rt) {
          union { unsigned u[2]; bf16x4 v; } pu;
          pu.u[0] = pk2bf(acc[ct][rt][0], acc[ct][rt][1]);
          pu.u[1] = pk2bf(acc[ct][rt][2], acc[ct][rt][3]);
          *(bf16x4*)&kL[(myrow + rt * 16 + c16) * 40 + ct * 16 + g * 4] = pu.v;
        }
    }
    // V: mfma(xf,Wf): lane = V[key myrow+rt*16+g*4+j][chan ct*16+c16] -> vL[chan][key]
    {
      f32x4 acc[2][2];
#pragma unroll
      for (int rt = 0; rt < 2; ++rt)
#pragma unroll
        for (int ct = 0; ct < 2; ++ct) acc[rt][ct] = zero4;
#pragma unroll
      for (int kk = 0; kk < 4; ++kk) {
        bf16x8 wf[2], xf[2];
#pragma unroll
        for (int ct = 0; ct < 2; ++ct)
          wf[ct] = *(const bf16x8*)(WT + (size_t)(512 + h * CH + ct * 16 + c16) * 128 + kk * 32 + g * 8);
#pragma unroll
        for (int rt = 0; rt < 2; ++rt)
          xf[rt] = *(const bf16x8*)&xl[(myrow + rt * 16 + c16) * 136 + kk * 32 + g * 8];
#pragma unroll
        for (int rt = 0; rt < 2; ++rt)
#pragma unroll
          for (int ct = 0; ct < 2; ++ct)
            acc[rt][ct] = __builtin_amdgcn_mfma_f32_16x16x32_bf16(xf[rt], wf[ct], acc[rt][ct], 0, 0, 0);
      }
#pragma unroll
      for (int rt = 0; rt < 2; ++rt)
#pragma unroll
        for (int ct = 0; ct < 2; ++ct) {
          union { unsigned u[2]; bf16x4 v; } pu;
          pu.u[0] = pk2bf(acc[rt][ct][0], acc[rt][ct][1]);
          pu.u[1] = pk2bf(acc[rt][ct][2], acc[rt][ct][3]);
          *(bf16x4*)&vL[(size_t)(ct * 16 + c16) * 264 + myrow + rt * 16 + g * 4] = pu.v;
        }
    }
    // Q: like K, seg 0 (scale pre-folded) -> qL[q][chan]
    {
      f32x4 acc[2][2];
#pragma unroll
      for (int ct = 0; ct < 2; ++ct)
#pragma unroll
        for (int rt = 0; rt < 2; ++rt) acc[ct][rt] = zero4;
#pragma unroll
      for (int kk = 0; kk < 4; ++kk) {
        bf16x8 wf[2], xf[2];
#pragma unroll
        for (int ct = 0; ct < 2; ++ct)
          wf[ct] = *(const bf16x8*)(WT + (size_t)(0 + h * CH + ct * 16 + c16) * 128 + kk * 32 + g * 8);
#pragma unroll
        for (int rt = 0; rt < 2; ++rt)
          xf[rt] = *(const bf16x8*)&xl[(myrow + rt * 16 + c16) * 136 + kk * 32 + g * 8];
#pragma unroll
        for (int ct = 0; ct < 2; ++ct)
#pragma unroll
          for (int rt = 0; rt < 2; ++rt)
            acc[ct][rt] = __builtin_amdgcn_mfma_f32_16x16x32_bf16(wf[ct], xf[rt], acc[ct][rt], 0, 0, 0);
      }
#pragma unroll
      for (int ct = 0; ct < 2; ++ct)
#pragma unroll
        for (int rt = 0; rt < 2; ++rt) {
          union { unsigned u[2]; bf16x4 v; } pu;
          pu.u[0] = pk2bf(acc[ct][rt][0], acc[ct][rt][1]);
          pu.u[1] = pk2bf(acc[ct][rt][2], acc[ct][rt][3]);
          *(bf16x4*)&qL[(myrow + rt * 16 + c16) * 40 + ct * 16 + g * 4] = pu.v;
        }
    }
    // G: mfma(xf,Wf) -> REGISTERS (O-fragment layout: q=g*4+i, chan=c16)
    {
#pragma unroll
      for (int rt = 0; rt < 2; ++rt)
#pragma unroll
        for (int ct = 0; ct < 2; ++ct) ga[rt][ct] = zero4;
#pragma unroll
      for (int kk = 0; kk < 4; ++kk) {
        bf16x8 wf[2], xf[2];
#pragma unroll
        for (int ct = 0; ct < 2; ++ct)
          wf[ct] = *(const bf16x8*)(WT + (size_t)(768 + h * CH + ct * 16 + c16) * 128 + kk * 32 + g * 8);
#pragma unroll
        for (int rt = 0; rt < 2; ++rt)
          xf[rt] = *(const bf16x8*)&xl[(myrow + rt * 16 + c16) * 136 + kk * 32 + g * 8];
#pragma unroll
        for (int rt = 0; rt < 2; ++rt)
#pragma unroll
          for (int ct = 0; ct < 2; ++ct)
            ga[rt][ct] = __builtin_amdgcn_mfma_f32_16x16x32_bf16(xf[rt], wf[ct], ga[rt][ct], 0, 0, 0);
      }
    }
    __syncthreads();   // A: kL/vL/qL visible to all waves

    // ================= attention phase (R1 body, 2 q-tiles/wave) =================
    const int qb = myrow;
    bf16x8 qf[2];
#pragma unroll
    for (int qt = 0; qt < 2; ++qt)
      qf[qt] = *(const bf16x8*)&qL[(qb + qt * 16 + c16) * 40 + g * 8];

    float l_[2] = {0.f, 0.f};
    f32x4 O[2][2];
#pragma unroll
    for (int qt = 0; qt < 2; ++qt) { O[qt][0] = zero4; O[qt][1] = zero4; }

    const float* bh = bias + (size_t)h * 65536;

#pragma unroll 1
    for (int ch = 0; ch < 8; ++ch) {
      float4 bb4[2][2];
#pragma unroll
      for (int kt = 0; kt < 2; ++kt)
#pragma unroll
        for (int qt = 0; qt < 2; ++qt)
          bb4[kt][qt] = *(const float4*)(bh + (size_t)(qb + qt * 16 + c16) * 256 +
                                         ch * 32 + kt * 16 + g * 4);

#pragma unroll
      for (int kt = 0; kt < 2; ++kt) {
        bf16x8 kf = *(const bf16x8*)&kL[(ch * 32 + kt * 16 + c16) * 40 + g * 8];
        bf16x4 vlo = *(const bf16x4*)&vL[(size_t)c16 * 264 + ch * 32 + kt * 16 + g * 4];
        bf16x4 vhi = *(const bf16x4*)&vL[(size_t)(16 + c16) * 264 + ch * 32 + kt * 16 + g * 4];
        const unsigned nib = (mb[ch] >> (kt * 16 + g * 4)) & 0xFu;
        float em[4];
#pragma unroll
        for (int i = 0; i < 4; ++i) em[i] = ((nib >> i) & 1u) ? 1.f : 0.f;
#pragma unroll
        for (int qt = 0; qt < 2; ++qt) {
          f32x4 S = __builtin_amdgcn_mfma_f32_16x16x32_bf16(kf, qf[qt], zero4, 0, 0, 0);
          float p0 = em[0] * __expf(fminf(S[0] + bb4[kt][qt].x, 85.f));
          float p1 = em[1] * __expf(fminf(S[1] + bb4[kt][qt].y, 85.f));
          float p2 = em[2] * __expf(fminf(S[2] + bb4[kt][qt].z, 85.f));
          float p3 = em[3] * __expf(fminf(S[3] + bb4[kt][qt].w, 85.f));
          l_[qt] += (p0 + p1) + (p2 + p3);
          union { unsigned u[2]; bf16x4 v; } pu;
          pu.u[0] = pk2bf(p0, p1);
          pu.u[1] = pk2bf(p2, p3);
          O[qt][0] = __builtin_amdgcn_mfma_f32_16x16x16bf16_1k(pu.v, vlo, O[qt][0], 0, 0, 0);
          O[qt][1] = __builtin_amdgcn_mfma_f32_16x16x16bf16_1k(pu.v, vhi, O[qt][1], 0, 0, 0);
        }
      }
    }

    // ---- l reduction over 4 g-groups (wave-local) ----
#pragma unroll
    for (int qt = 0; qt < 2; ++qt) {
      float v = l_[qt];
      v += __shfl_xor(v, 16);
      v += __shfl_xor(v, 32);
      if (lane < 16) lL[myrow + qt * 16 + c16] = v;
    }

    // ---- epilogue: gated O -> bf16 -> qL reused as oL (wave-private rows) ----
    {
      float bgl0 = bg[h * CH + c16];
      float bgl1 = bg[h * CH + 16 + c16];
#pragma unroll
      for (int qt = 0; qt < 2; ++qt)
#pragma unroll
        for (int i = 0; i < 4; ++i) {
          int row = qb + qt * 16 + g * 4 + i;
          float inv = 1.f / lL[myrow + qt * 16 + g * 4 + i];
          float g0 = 1.f / (1.f + __expf(-(ga[qt][0][i] + bgl0)));
          float g1 = 1.f / (1.f + __expf(-(ga[qt][1][i] + bgl1)));
          qL[row * 40 + c16]      = f2bf(O[qt][0][i] * inv * g0);
          qL[row * 40 + 16 + c16] = f2bf(O[qt][1][i] * inv * g1);
        }
    }

    // ---- out accumulation: acc_out[qt][ct] += O_h(16x32) @ Wo[h*32..][ct*16..] ----
    {
      bf16x8 wo[8];
#pragma unroll
      for (int ct = 0; ct < 8; ++ct)
        wo[ct] = *(const bf16x8*)(WoT + (size_t)(ct * 16 + c16) * 256 + h * 32 + g * 8);
#pragma unroll
      for (int qt = 0; qt < 2; ++qt) {
        bf16x8 of = *(const bf16x8*)&qL[(qb + qt * 16 + c16) * 40 + g * 8];
#pragma unroll
        for (int ct = 0; ct < 8; ++ct)
          acc_out[qt][ct] = __builtin_amdgcn_mfma_f32_16x16x32_bf16(of, wo[ct], acc_out[qt][ct], 0, 0, 0);
      }
    }
    __syncthreads();   // B: kL/vL/qL reads done before next head's proj overwrites
  }

  // ---- final: out = acc_out + bo (f32 direct) ----
#pragma unroll
  for (int ct = 0; ct < 8; ++ct) {
    float bv = bo[ct * 16 + c16];
#pragma unroll
    for (int qt = 0; qt < 2; ++qt)
#pragma unroll
      for (int i = 0; i < 4; ++i)
        out[((size_t)srow * 256 + myrow + qt * 16 + g * 4 + i) * 128 + ct * 16 + c16] =
            acc_out[qt][ct][i] + bv;
  }
}

extern "C" void kernel_launch(void* const* d_in, const int* in_sizes, int n_in,
                              void* d_out, int out_size, void* d_ws, size_t ws_size,
                              hipStream_t stream) {
  const float* x    = (const float*)d_in[0];
  const float* bias = (const float*)d_in[1];
  const void*  mask = d_in[2];
  const float* Wq   = (const float*)d_in[3];
  const float* Wk   = (const float*)d_in[4];
  const float* Wv   = (const float*)d_in[5];
  const float* Wo   = (const float*)d_in[6];
  const float* bo   = (const float*)d_in[7];
  const float* Wg   = (const float*)d_in[8];
  const float* bg   = (const float*)d_in[9];
  float* out = (float*)d_out;

  // ws: [flag 256B][WT 256KB][WoT 64KB]
  unsigned int* flag = (unsigned int*)d_ws;
  short* WT  = (short*)((char*)d_ws + 256);
  short* WoT = WT + 131072;

  prep<<<41, 256, 0, stream>>>(Wq, Wk, Wv, Wg, Wo, (const uint4*)mask,
                               WT, WoT, flag);
  fused_attn<<<256, 512, 0, stream>>>(x, WT, WoT, bias, bg, bo,
                                      mask, flag, out);
}